// Round 4
// baseline (4320.938 us; speedup 1.0000x reference)
//
#include <hip/hip_runtime.h>
#include <hip/hip_cooperative_groups.h>
#include <cstdint>
#include <cstddef>

namespace cg = cooperative_groups;

#define BATCHN 8
#define TLEN   3200
#define NCH    512
#define BCH    128
#define HCH    512
#define LBLK   24
#define CNTF   (512.0f * 3200.0f)
#define EPSV   1e-8f
#define NSLOT  32
#define NBLK   200          // persistent blocks: 25 per sample, 128 rows each

typedef float  floatx4 __attribute__((ext_vector_type(4)));
typedef short  short8  __attribute__((ext_vector_type(8)));
typedef short  short4v __attribute__((ext_vector_type(4)));

__device__ inline unsigned short f2bf(float f) {
    unsigned int u = __float_as_uint(f);
    u = (u + 0x7fffu + ((u >> 16) & 1u)) >> 16;
    return (unsigned short)u;
}
__device__ inline float bf2f(short s) {
    return __uint_as_float(((unsigned int)(unsigned short)s) << 16);
}

__device__ inline void block_reduce_atomic2(float s, float ss, float* out) {
#pragma unroll
    for (int off = 32; off; off >>= 1) {
        s  += __shfl_down(s, off, 64);
        ss += __shfl_down(ss, off, 64);
    }
    __shared__ float pr[16];
    const int wave = threadIdx.x >> 6;
    const int lane = threadIdx.x & 63;
    if (lane == 0) { pr[wave * 2] = s; pr[wave * 2 + 1] = ss; }
    __syncthreads();
    if (threadIdx.x == 0) {
        const int nw = blockDim.x >> 6;
        float a = 0.f, b = 0.f;
        for (int i = 0; i < nw; i++) { a += pr[i * 2]; b += pr[i * 2 + 1]; }
        atomicAdd(out, a);
        atomicAdd(out + 1, b);
    }
    __syncthreads();
}

__device__ inline void load_stats32(const float* __restrict__ st,
                                    float& mu, float& rstd) {
    float s = 0.f, ss = 0.f;
#pragma unroll
    for (int i = 0; i < NSLOT; i++) { s += st[2 * i]; ss += st[2 * i + 1]; }
    mu = s * (1.f / CNTF);
    const float var = ss * (1.f / CNTF) - mu * mu;
    rstd = rsqrtf(var + EPSV);
}

// ---------------------------------------------------------------------------
// Persistent cooperative kernel: all 24 TCN blocks. 200 blocks x 512 threads.
// Block owns rows [blk*128, +128) of flattened [B*T][*]. feats (res-waves) and
// skip-accumulator (skip-waves) live in registers (pacc); feats bf16 mirror in
// LDS. h / hd round-trip global (L2/L3). 2 grid syncs per iteration.
// ---------------------------------------------------------------------------
struct PArgs {
    const unsigned short* W1b;    // [24][512][128] bf16
    const unsigned short* WsrG;   // [24][256][512] bf16: rows 0..127 skip*g2, 128..255 res*g2
    const float* b1;              // [24][512]
    const float* a1;              // [24]
    const float* a2;              // [24]
    const float* g1;              // [24][512]
    const float* be1;             // [24][512]
    const float* bd;              // [24][512]
    const float* wdt;             // [24][3][512] transposed dw weights
    const float* bskip;           // [24][128]
    const float* bres;            // [24][128]
    const float* uv_s;            // [24][2][128]
    const float* uv_r;            // [24][2][128]
    const float* feats;           // [25600][128] fp32 (from mm_first)
    unsigned short* h;            // [25600][512] bf16
    unsigned short* hd;           // [25600][512] bf16
    unsigned short* outbf;        // [25600][128] bf16 = PReLU(outAcc, a_out)
    float* stats;                 // 49 slots x [8][32][2]
    const float* aout;            // [1]
};

__global__ __launch_bounds__(512, 2) void persist_k(PArgs p) {
    cg::grid_group grid = cg::this_grid();

    const int blk  = blockIdx.x;          // 0..199
    const int b    = blk / 25;
    const int tb   = (blk % 25) * 128;    // sample-local t base
    const int row0 = b * TLEN + tb;       // global row base
    const int slot = blk % 25;            // contention-free stat slot (<32)
    const int tid  = threadIdx.x;
    const int wid  = tid >> 6;            // 0..7
    const int lane = tid & 63;
    const int l15  = lane & 15;
    const int quad = lane >> 4;
    const int wt   = wid & 1;             // t-half (64 rows)
    const int wc   = wid >> 1;            // 0..3 col quarter

    __shared__ __align__(16) unsigned short fbf[128 * 136];  // feats bf16, padded

    // ---- phase 0: init LDS feats mirror + persistent registers ----
    for (int idx = tid; idx < 128 * 16; idx += 512) {
        const int rowl = idx >> 4, ch = idx & 15;
        const float* fp = p.feats + (size_t)(row0 + rowl) * BCH + ch * 8;
        const float4 v0 = *reinterpret_cast<const float4*>(fp);
        const float4 v1 = *reinterpret_cast<const float4*>(fp + 4);
        short8 s;
        s[0]=(short)f2bf(v0.x); s[1]=(short)f2bf(v0.y);
        s[2]=(short)f2bf(v0.z); s[3]=(short)f2bf(v0.w);
        s[4]=(short)f2bf(v1.x); s[5]=(short)f2bf(v1.y);
        s[6]=(short)f2bf(v1.z); s[7]=(short)f2bf(v1.w);
        *reinterpret_cast<short8*>(&fbf[rowl * 136 + ch * 8]) = s;
    }

    floatx4 pacc[4][4];   // skip-waves (wc<2): outAcc; res-waves (wc>=2): feats
    if (wc < 2) {
#pragma unroll
        for (int ii = 0; ii < 4; ii++)
#pragma unroll
            for (int jj = 0; jj < 4; jj++)
#pragma unroll
                for (int r = 0; r < 4; r++) pacc[ii][jj][r] = 0.f;
    } else {
#pragma unroll
        for (int ii = 0; ii < 4; ii++)
#pragma unroll
            for (int jj = 0; jj < 4; jj++)
#pragma unroll
                for (int r = 0; r < 4; r++)
                    pacc[ii][jj][r] = p.feats[(size_t)(row0 + wt*64 + ii*16 + quad*4 + r) * BCH
                                              + (wc - 2) * 64 + jj * 16 + l15];
    }
    __syncthreads();

    for (int i = 0; i < LBLK; i++) {
        const int dil = 1 << (i & 7);
        float* st_h  = p.stats + (size_t)(1 + 2 * i) * (BATCHN * 2 * NSLOT);
        float* st_hd = p.stats + (size_t)(2 + 2 * i) * (BATCHN * 2 * NSLOT);

        // ===== phase A: h = PReLU(W1 @ feats + b1, a1), stats(h) =====
        {
            const float a1v = p.a1[i];
            float ssum = 0.f, ssq = 0.f;
            for (int pass = 0; pass < 2; ++pass) {
                floatx4 acc[4][4];
#pragma unroll
                for (int ii = 0; ii < 4; ii++)
#pragma unroll
                    for (int jj = 0; jj < 4; jj++)
#pragma unroll
                        for (int r = 0; r < 4; r++) acc[ii][jj][r] = 0.f;

                const unsigned short* Wb = p.W1b + (size_t)i * HCH * BCH
                    + (size_t)(pass * 256 + wc * 64 + l15) * BCH + quad * 8;
#pragma unroll 2
                for (int kc = 0; kc < 4; ++kc) {
                    short8 a[4], w[4];
#pragma unroll
                    for (int ii = 0; ii < 4; ii++)
                        a[ii] = *reinterpret_cast<const short8*>(
                            &fbf[(wt*64 + ii*16 + l15) * 136 + kc * 32 + quad * 8]);
#pragma unroll
                    for (int jj = 0; jj < 4; jj++)
                        w[jj] = *reinterpret_cast<const short8*>(Wb + (size_t)jj*16*BCH + kc*32);
#pragma unroll
                    for (int ii = 0; ii < 4; ii++)
#pragma unroll
                        for (int jj = 0; jj < 4; jj++)
                            acc[ii][jj] = __builtin_amdgcn_mfma_f32_16x16x32_bf16(
                                a[ii], w[jj], acc[ii][jj], 0, 0, 0);
                }
#pragma unroll
                for (int jj = 0; jj < 4; jj++) {
                    const int c = pass * 256 + wc * 64 + jj * 16 + l15;
                    const float bz = p.b1[(size_t)i * HCH + c];
#pragma unroll
                    for (int ii = 0; ii < 4; ii++) {
                        const int rowl = wt * 64 + ii * 16 + quad * 4;
#pragma unroll
                        for (int r = 0; r < 4; r++) {
                            float v = acc[ii][jj][r] + bz;
                            v = v >= 0.f ? v : a1v * v;
                            ssum += v; ssq += v * v;
                            p.h[(size_t)(row0 + rowl + r) * HCH + c] = f2bf(v);
                        }
                    }
                }
            }
            block_reduce_atomic2(ssum, ssq, st_h + b * 64 + slot * 2);
        }
        __threadfence();
        grid.sync();

        // ===== phase B: hd = PReLU(dwconv(gln1(h)) + bd, a2), stats(hd) =====
        {
            float mu1, rstd1;
            load_stats32(st_h + b * 64, mu1, rstd1);
            const float a2v = p.a2[i];
            const int c0 = lane * 8;
            const float* wdtL = p.wdt + (size_t)i * 3 * HCH;
            float w0v[8], w1v[8], w2v[8], gv[8], bev[8], bdv[8];
#pragma unroll
            for (int q = 0; q < 2; q++) {
                const float4 a0 = *reinterpret_cast<const float4*>(wdtL + c0 + q*4);
                const float4 a1_ = *reinterpret_cast<const float4*>(wdtL + HCH + c0 + q*4);
                const float4 a2_ = *reinterpret_cast<const float4*>(wdtL + 2*HCH + c0 + q*4);
                const float4 gg = *reinterpret_cast<const float4*>(p.g1 + (size_t)i*HCH + c0 + q*4);
                const float4 bb = *reinterpret_cast<const float4*>(p.be1 + (size_t)i*HCH + c0 + q*4);
                const float4 dd = *reinterpret_cast<const float4*>(p.bd + (size_t)i*HCH + c0 + q*4);
                const float* a0p = &a0.x; const float* a1p = &a1_.x; const float* a2p = &a2_.x;
                const float* ggp = &gg.x; const float* bbp = &bb.x; const float* ddp = &dd.x;
#pragma unroll
                for (int j = 0; j < 4; j++) {
                    w0v[q*4+j] = a0p[j]; w1v[q*4+j] = a1p[j]; w2v[q*4+j] = a2p[j];
                    gv[q*4+j]  = ggp[j] * rstd1;
                    bev[q*4+j] = bbp[j] - mu1 * rstd1 * ggp[j];
                    bdv[q*4+j] = ddp[j];
                }
            }
            const int rbase = wid * 16;  // local rows [rbase, rbase+16)
            float ssum = 0.f, ssq = 0.f;
            for (int rr = 0; rr < 16; ++rr) {
                const int tl = tb + rbase + rr;   // sample-local t (wave-uniform)
                const size_t off = (size_t)(row0 + rbase + rr) * HCH + c0;
                const bool hasP = tl - dil >= 0;
                const bool hasN = tl + dil < TLEN;
                const short8 cur = *reinterpret_cast<const short8*>(p.h + off);
                short8 prv = {0,0,0,0,0,0,0,0}, nxt = {0,0,0,0,0,0,0,0};
                if (hasP) prv = *reinterpret_cast<const short8*>(p.h + off - (size_t)dil * HCH);
                if (hasN) nxt = *reinterpret_cast<const short8*>(p.h + off + (size_t)dil * HCH);
                short8 o;
#pragma unroll
                for (int j = 0; j < 8; j++) {
                    float conv = w1v[j] * bf2f(cur[j]);
                    float s = w1v[j];
                    if (hasP) { conv += w0v[j] * bf2f(prv[j]); s += w0v[j]; }
                    if (hasN) { conv += w2v[j] * bf2f(nxt[j]); s += w2v[j]; }
                    float v = gv[j] * conv + bdv[j] + bev[j] * s;
                    v = v >= 0.f ? v : a2v * v;
                    o[j] = (short)f2bf(v);
                    ssum += v; ssq += v * v;
                }
                *reinterpret_cast<short8*>(p.hd + off) = o;
            }
            block_reduce_atomic2(ssum, ssq, st_hd + b * 64 + slot * 2);
        }

        // ===== phase C mainloop: (skip|res) GEMM on own hd rows =====
        floatx4 acc[4][4];
#pragma unroll
        for (int ii = 0; ii < 4; ii++)
#pragma unroll
            for (int jj = 0; jj < 4; jj++)
#pragma unroll
                for (int r = 0; r < 4; r++) acc[ii][jj][r] = 0.f;
        {
            const unsigned short* Wb = p.WsrG + (size_t)i * 256 * HCH
                + (size_t)(wc * 64 + l15) * HCH + quad * 8;
            const unsigned short* Ab = p.hd
                + (size_t)(row0 + wt * 64 + l15) * HCH + quad * 8;
#pragma unroll 2
            for (int kc = 0; kc < 16; ++kc) {
                short8 a[4], w[4];
#pragma unroll
                for (int ii = 0; ii < 4; ii++)
                    a[ii] = *reinterpret_cast<const short8*>(Ab + (size_t)ii*16*HCH + kc*32);
#pragma unroll
                for (int jj = 0; jj < 4; jj++)
                    w[jj] = *reinterpret_cast<const short8*>(Wb + (size_t)jj*16*HCH + kc*32);
#pragma unroll
                for (int ii = 0; ii < 4; ii++)
#pragma unroll
                    for (int jj = 0; jj < 4; jj++)
                        acc[ii][jj] = __builtin_amdgcn_mfma_f32_16x16x32_bf16(
                            a[ii], w[jj], acc[ii][jj], 0, 0, 0);
            }
        }
        __threadfence();
        grid.sync();

        // ===== phase C epilogue: stats(hd) -> fold gLN2, update pacc =====
        {
            float mu2, rstd2;
            load_stats32(st_hd + b * 64, mu2, rstd2);
#pragma unroll
            for (int jj = 0; jj < 4; jj++) {
                const int cS = wc * 64 + jj * 16 + l15;
                float rb;
                if (wc < 2) {
                    rb = p.bskip[(size_t)i * BCH + cS]
                       + p.uv_s[(size_t)i * 256 + cS]
                       - mu2 * rstd2 * p.uv_s[(size_t)i * 256 + BCH + cS];
                } else {
                    const int c = cS - BCH;
                    rb = p.bres[(size_t)i * BCH + c]
                       + p.uv_r[(size_t)i * 256 + c]
                       - mu2 * rstd2 * p.uv_r[(size_t)i * 256 + BCH + c];
                }
#pragma unroll
                for (int ii = 0; ii < 4; ii++) {
#pragma unroll
                    for (int r = 0; r < 4; r++) {
                        const float v = rstd2 * acc[ii][jj][r] + rb;
                        pacc[ii][jj][r] += v;
                        if (wc >= 2)
                            fbf[(wt*64 + ii*16 + quad*4 + r) * 136 + (cS - BCH)] =
                                f2bf(pacc[ii][jj][r]);
                    }
                }
            }
        }
        __syncthreads();
    }

    // ---- final: outbf = PReLU(outAcc, a_out) in bf16 ----
    if (wc < 2) {
        const float ao = p.aout[0];
#pragma unroll
        for (int jj = 0; jj < 4; jj++) {
            const int c = wc * 64 + jj * 16 + l15;
#pragma unroll
            for (int ii = 0; ii < 4; ii++) {
#pragma unroll
                for (int r = 0; r < 4; r++) {
                    float v = pacc[ii][jj][r];
                    v = v >= 0.f ? v : ao * v;
                    p.outbf[(size_t)(row0 + wt*64 + ii*16 + quad*4 + r) * BCH + c] = f2bf(v);
                }
            }
        }
    }
}

// ---------------------------------------------------------------------------
// First conv: feats = rstd*(WcG @ x_t) + rowbias. Tile 128t x 128c, 4 waves.
// ---------------------------------------------------------------------------
__global__ __launch_bounds__(256, 2) void mm_first_k(
    const unsigned short* __restrict__ xt, const unsigned short* __restrict__ WcG,
    const float* __restrict__ bc, const float* __restrict__ uv,
    const float* __restrict__ stats, float* __restrict__ feats)
{
    const int b    = blockIdx.y;
    const int row0 = b * TLEN + blockIdx.x * 128;
    const int lane = threadIdx.x & 63;
    const int wid  = threadIdx.x >> 6;
    const int wt   = wid & 1;
    const int wm   = wid >> 1;
    const int l15  = lane & 15;
    const int quad = lane >> 4;

    float mu, rstd;
    load_stats32(stats + b * 64, mu, rstd);

    floatx4 acc[4][4];
#pragma unroll
    for (int ii = 0; ii < 4; ii++)
#pragma unroll
        for (int jj = 0; jj < 4; jj++)
#pragma unroll
            for (int r = 0; r < 4; r++) acc[ii][jj][r] = 0.f;

    const unsigned short* Ab = xt + (size_t)(row0 + wt*64 + l15) * NCH + quad * 8;
    const unsigned short* Wb = WcG + (size_t)(wm*64 + l15) * NCH + quad * 8;
#pragma unroll 2
    for (int kc = 0; kc < 16; ++kc) {
        short8 a[4], w[4];
#pragma unroll
        for (int ii = 0; ii < 4; ii++)
            a[ii] = *reinterpret_cast<const short8*>(Ab + (size_t)ii*16*NCH + kc*32);
#pragma unroll
        for (int jj = 0; jj < 4; jj++)
            w[jj] = *reinterpret_cast<const short8*>(Wb + (size_t)jj*16*NCH + kc*32);
#pragma unroll
        for (int ii = 0; ii < 4; ii++)
#pragma unroll
            for (int jj = 0; jj < 4; jj++)
                acc[ii][jj] = __builtin_amdgcn_mfma_f32_16x16x32_bf16(
                    a[ii], w[jj], acc[ii][jj], 0, 0, 0);
    }
#pragma unroll
    for (int jj = 0; jj < 4; jj++) {
        const int c = wm * 64 + jj * 16 + l15;
        const float rb = bc[c] + uv[c] - mu * rstd * uv[BCH + c];
#pragma unroll
        for (int ii = 0; ii < 4; ii++) {
#pragma unroll
            for (int r = 0; r < 4; r++) {
                feats[(size_t)(row0 + wt*64 + ii*16 + quad*4 + r) * BCH + c] =
                    rstd * acc[ii][jj][r] + rb;
            }
        }
    }
}

// ---------------------------------------------------------------------------
// Final GEMM: out[b][m][t] = sigmoid(Wo @ act + bo), act = outbf (bf16).
// ---------------------------------------------------------------------------
__global__ __launch_bounds__(256, 2) void mm_final_k(
    const unsigned short* __restrict__ act, const unsigned short* __restrict__ Wb,
    const float* __restrict__ bo, float* __restrict__ out)
{
    const int b    = blockIdx.z;
    const int t0   = blockIdx.x * 128;
    const int m0   = blockIdx.y * 128;
    const int lane = threadIdx.x & 63;
    const int wid  = threadIdx.x >> 6;
    const int wcol = wid & 1;    // t half
    const int wrow = wid >> 1;   // m half
    const int l15  = lane & 15;
    const int quad = lane >> 4;

    const unsigned short* Wp = Wb + (size_t)(m0 + wrow*64 + l15) * BCH + quad * 8;
    const unsigned short* Xp = act + (size_t)(b * TLEN + t0 + wcol*64 + l15) * BCH + quad * 8;

    floatx4 acc[4][4];
#pragma unroll
    for (int i = 0; i < 4; i++)
#pragma unroll
        for (int j = 0; j < 4; j++)
#pragma unroll
            for (int r = 0; r < 4; r++) acc[i][j][r] = 0.f;

#pragma unroll
    for (int kc = 0; kc < BCH / 32; ++kc) {
        short8 a[4], x[4];
#pragma unroll
        for (int i = 0; i < 4; i++)
            a[i] = *reinterpret_cast<const short8*>(Wp + (size_t)i*16*BCH + kc*32);
#pragma unroll
        for (int j = 0; j < 4; j++)
            x[j] = *reinterpret_cast<const short8*>(Xp + (size_t)j*16*BCH + kc*32);
#pragma unroll
        for (int i = 0; i < 4; i++)
#pragma unroll
            for (int j = 0; j < 4; j++)
                acc[i][j] = __builtin_amdgcn_mfma_f32_16x16x32_bf16(
                    a[i], x[j], acc[i][j], 0, 0, 0);
    }

#pragma unroll
    for (int i = 0; i < 4; i++) {
        const int mb = m0 + wrow * 64 + i * 16 + quad * 4;
#pragma unroll
        for (int r = 0; r < 4; r++) {
            const int m = mb + r;
            const float bz = bo[m];
#pragma unroll
            for (int j = 0; j < 4; j++) {
                const int t = t0 + wcol * 64 + j * 16 + l15;
                float val = acc[i][j][r] + bz;
                val = 1.f / (1.f + expf(-val));
                out[((size_t)b * (2 * NCH) + m) * TLEN + t] = val;
            }
        }
    }
}

// Weight prep with inter-matrix output stride (for skip|res concat).
__global__ __launch_bounds__(256) void prep_w_k(
    const float* __restrict__ W, const float* __restrict__ g,
    const float* __restrict__ be, unsigned short* __restrict__ Wout,
    float* __restrict__ uv, int Mrows, int K, int nmat, int outMatStride)
{
    const int r    = blockIdx.x * 4 + (threadIdx.x >> 6);
    const int lane = threadIdx.x & 63;
    if (r >= Mrows * nmat) return;
    const int mat = r / Mrows;
    const int m   = r - mat * Mrows;
    const float* Wrow = W + (size_t)r * K;
    const float* gv = g  ? g  + (size_t)mat * K : nullptr;
    const float* bv = be ? be + (size_t)mat * K : nullptr;
    unsigned short* Orow = Wout + (size_t)mat * outMatStride + (size_t)m * K;
    float u = 0.f, v = 0.f;
    for (int k = lane * 4; k < K; k += 256) {
        float4 w4 = *reinterpret_cast<const float4*>(Wrow + k);
        float4 o4 = w4;
        if (gv) {
            const float4 g4 = *reinterpret_cast<const float4*>(gv + k);
            const float4 b4 = *reinterpret_cast<const float4*>(bv + k);
            o4.x = w4.x * g4.x; o4.y = w4.y * g4.y;
            o4.z = w4.z * g4.z; o4.w = w4.w * g4.w;
            u += w4.x * b4.x + w4.y * b4.y + w4.z * b4.z + w4.w * b4.w;
            v += w4.x * g4.x + w4.y * g4.y + w4.z * g4.z + w4.w * g4.w;
        }
        short4v s;
        s[0] = (short)f2bf(o4.x); s[1] = (short)f2bf(o4.y);
        s[2] = (short)f2bf(o4.z); s[3] = (short)f2bf(o4.w);
        *reinterpret_cast<short4v*>(Orow + k) = s;
    }
    if (gv && uv) {
#pragma unroll
        for (int off = 32; off; off >>= 1) {
            u += __shfl_down(u, off, 64);
            v += __shfl_down(v, off, 64);
        }
        if (lane == 0) {
            uv[(size_t)mat * 2 * Mrows + m]         = u;
            uv[(size_t)mat * 2 * Mrows + Mrows + m] = v;
        }
    }
}

// Wd [24*512][3] -> wdt [24][3][512]
__global__ void prep_dwt_k(const float* __restrict__ Wd, float* __restrict__ wdt)
{
    const int i = blockIdx.x;
    const int c = threadIdx.x;
#pragma unroll
    for (int tap = 0; tap < 3; tap++)
        wdt[(size_t)i * 3 * HCH + tap * HCH + c] = Wd[((size_t)i * HCH + c) * 3 + tap];
}

// Transpose + bf16 cvt + input gLN stats, fused.
__global__ __launch_bounds__(256) void tr_x_k(
    const float* __restrict__ x, unsigned short* __restrict__ xt,
    float* __restrict__ statsOut)
{
    __shared__ unsigned short tile[32][33];
    const int b  = blockIdx.z;
    const int t0 = blockIdx.x * 32;
    const int c0 = blockIdx.y * 32;
    const int tx = threadIdx.x & 31;
    const int ty = threadIdx.x >> 5;
    float s = 0.f, ss = 0.f;
#pragma unroll
    for (int r = 0; r < 4; r++) {
        const int cl = ty + r * 8;
        const float v = x[((size_t)b * NCH + c0 + cl) * TLEN + t0 + tx];
        s += v; ss += v * v;
        tile[tx][cl] = f2bf(v);
    }
    __syncthreads();
#pragma unroll
    for (int r = 0; r < 4; r++) {
        const int tl = ty + r * 8;
        xt[((size_t)b * TLEN + t0 + tl) * NCH + c0 + tx] = tile[tl][tx];
    }
    block_reduce_atomic2(s, ss,
        statsOut + b * (2 * NSLOT) + ((blockIdx.x * 16 + blockIdx.y) & (NSLOT - 1)) * 2);
}

extern "C" void kernel_launch(void* const* d_in, const int* in_sizes, int n_in,
                              void* d_out, int out_size, void* d_ws, size_t ws_size,
                              hipStream_t stream)
{
    (void)in_sizes; (void)n_in; (void)out_size; (void)ws_size;

    const float* x    = (const float*)d_in[0];
    const float* in_g = (const float*)d_in[1];
    const float* in_b = (const float*)d_in[2];
    const float* Wc   = (const float*)d_in[3];
    const float* bc   = (const float*)d_in[4];
    const float* W1   = (const float*)d_in[5];
    const float* b1   = (const float*)d_in[6];
    const float* a1   = (const float*)d_in[7];
    const float* g1   = (const float*)d_in[8];
    const float* be1  = (const float*)d_in[9];
    const float* Wd   = (const float*)d_in[10];
    const float* bd   = (const float*)d_in[11];
    const float* a2   = (const float*)d_in[12];
    const float* g2   = (const float*)d_in[13];
    const float* be2  = (const float*)d_in[14];
    const float* Wres = (const float*)d_in[15];
    const float* bres = (const float*)d_in[16];
    const float* Wskip= (const float*)d_in[17];
    const float* bskip= (const float*)d_in[18];
    const float* aout = (const float*)d_in[19];
    const float* Wo   = (const float*)d_in[20];
    const float* bo   = (const float*)d_in[21];
    float* out = (float*)d_out;

    const size_t ROWS = (size_t)BATCHN * TLEN;   // 25600

    uint8_t* p = (uint8_t*)d_ws;
    unsigned short* x_t   = (unsigned short*)p; p += ROWS * NCH * 2;
    float*          feats = (float*)p;          p += ROWS * BCH * 4;
    unsigned short* outbf = (unsigned short*)p; p += ROWS * BCH * 2;
    unsigned short* h     = (unsigned short*)p; p += ROWS * HCH * 2;
    unsigned short* hd    = (unsigned short*)p; p += ROWS * HCH * 2;
    unsigned short* WcG   = (unsigned short*)p; p += (size_t)BCH * NCH * 2;
    unsigned short* W1b   = (unsigned short*)p; p += (size_t)LBLK * HCH * BCH * 2;
    unsigned short* WsrG  = (unsigned short*)p; p += (size_t)LBLK * 256 * HCH * 2;
    unsigned short* Wob   = (unsigned short*)p; p += (size_t)(2 * NCH) * BCH * 2;
    float*          wdt   = (float*)p;          p += (size_t)LBLK * 3 * HCH * 4;
    float*          uv_c  = (float*)p;          p += (size_t)2 * BCH * 4;
    float*          uv_s  = (float*)p;          p += (size_t)LBLK * 2 * BCH * 4;
    float*          uv_r  = (float*)p;          p += (size_t)LBLK * 2 * BCH * 4;
    float*          stats = (float*)p;

    const size_t SLOTF = (size_t)BATCHN * 2 * NSLOT;

    hipMemsetAsync(stats, 0, (size_t)49 * SLOTF * sizeof(float), stream);

    // ---- prep ----
    tr_x_k<<<dim3(100, 16, BATCHN), 256, 0, stream>>>(x, x_t, stats);
    prep_w_k<<<32,   256, 0, stream>>>(Wc,   in_g, in_b, WcG, uv_c, BCH, NCH, 1, BCH*NCH);
    prep_w_k<<<3072, 256, 0, stream>>>(W1,   nullptr, nullptr, W1b, nullptr, HCH, BCH, LBLK, HCH*BCH);
    prep_w_k<<<768,  256, 0, stream>>>(Wskip, g2, be2, WsrG,            uv_s, BCH, HCH, LBLK, 256*HCH);
    prep_w_k<<<768,  256, 0, stream>>>(Wres,  g2, be2, WsrG + 128*HCH,  uv_r, BCH, HCH, LBLK, 256*HCH);
    prep_w_k<<<256,  256, 0, stream>>>(Wo,   nullptr, nullptr, Wob, nullptr, 2*NCH, BCH, 1, 2*NCH*BCH);
    prep_dwt_k<<<LBLK, HCH, 0, stream>>>(Wd, wdt);

    // ---- first conv ----
    mm_first_k<<<dim3(25, BATCHN), 256, 0, stream>>>(x_t, WcG, bc, uv_c, stats, feats);

    // ---- persistent TCN ----
    PArgs pa;
    pa.W1b = W1b; pa.WsrG = WsrG;
    pa.b1 = b1; pa.a1 = a1; pa.a2 = a2;
    pa.g1 = g1; pa.be1 = be1; pa.bd = bd; pa.wdt = wdt;
    pa.bskip = bskip; pa.bres = bres; pa.uv_s = uv_s; pa.uv_r = uv_r;
    pa.feats = feats; pa.h = h; pa.hd = hd; pa.outbf = outbf;
    pa.stats = stats; pa.aout = aout;
    void* kp[] = { &pa };
    hipLaunchCooperativeKernel((const void*)persist_k, dim3(NBLK), dim3(512),
                               kp, 0, stream);

    // ---- final conv + sigmoid ----
    mm_final_k<<<dim3(25, 8, BATCHN), 256, 0, stream>>>(outbf, Wob, bo, out);
}